// Round 4
// baseline (232.017 us; speedup 1.0000x reference)
//
#include <hip/hip_runtime.h>
#include <hip/hip_bf16.h>
#include <stdint.h>
#include <stddef.h>

// ---------------------------------------------------------------------------
// Quantized LSTM cell (B=4096, I=H=1024) with JAX threefry noise reproduction.
//
// gates = qS8(input) @ (Wih^T + n0) + b_ih + nb0 + qS8(hx) @ (Whh^T + n1) + b_hh + nb1
// ONE bf16 MFMA GEMM, M=N=K=4096:
//   A  [4096][2048] = [qS8(input) | qS8(hx)]          (exact in bf16)
//   B^T[4096][4096] = rows k<2048: bf16_hi(Weff), k>=2048: bf16_lo(Weff)
//   B columns PERMUTED: col' = 4*h + gate  -> LSTM epilogue fused into GEMM.
//
// GEMM: 256x256 tile, BK=32, 8 waves (2Mx4N), 4-deep LDS pipeline (128KB),
// m201-style phase schedule: 2 phases/K-tile, 16 MFMA/phase (acc quadrant
// rotation), reads+stages issued between barriers so the matrix pipe drains
// the previous phase while the LDS pipe serves the next; counted vmcnt(4).
// ---------------------------------------------------------------------------

#define PART 1

typedef __attribute__((ext_vector_type(8))) short bf16x8;
typedef __attribute__((ext_vector_type(4))) float f32x4;

#define BATCH 4096

// ---- workspace layout (bytes) ----
#define WS_A_OFF    ((size_t)0)                 // ushort[4096*2048]   16 MiB
#define WS_B_OFF    ((size_t)16 << 20)          // ushort[4096*4096]   32 MiB
#define WS_BIAS_OFF ((size_t)48 << 20)          // float [4096]
#define WS_MAX_OFF  (WS_BIAS_OFF + 16384)       // uint32[4]

// ---------------- threefry2x32 (exact JAX algorithm) ----------------
__host__ __device__ inline void tf2x32(uint32_t k0, uint32_t k1,
                                       uint32_t x0, uint32_t x1,
                                       uint32_t &o0, uint32_t &o1)
{
  const uint32_t k2 = k0 ^ k1 ^ 0x1BD11BDAu;
#define TFR(r) { x0 += x1; x1 = (x1 << (r)) | (x1 >> (32 - (r))); x1 ^= x0; }
  x0 += k0; x1 += k1;
  TFR(13) TFR(15) TFR(26) TFR(6)
  x0 += k1; x1 += k2 + 1u;
  TFR(17) TFR(29) TFR(16) TFR(24)
  x0 += k2; x1 += k0 + 2u;
  TFR(13) TFR(15) TFR(26) TFR(6)
  x0 += k0; x1 += k1 + 3u;
  TFR(17) TFR(29) TFR(16) TFR(24)
  x0 += k1; x1 += k2 + 4u;
  TFR(13) TFR(15) TFR(26) TFR(6)
  x0 += k2; x1 += k0 + 5u;
#undef TFR
  o0 = x0; o1 = x1;
}

__device__ inline uint32_t jax_bits32(uint32_t k0, uint32_t k1, uint32_t i, uint32_t size)
{
#if PART
  uint32_t a, b;
  tf2x32(k0, k1, 0u, i, a, b);
  return a ^ b;
#else
  uint32_t half = size >> 1, a, b;
  if (i < half) { tf2x32(k0, k1, i, i + half, a, b); return a; }
  tf2x32(k0, k1, i - half, i, a, b); return b;
#endif
}

// uniform(-1+2^-24, 1) -> sqrt(2)*erfinv(u), XLA f32 ErfInv (Giles) polynomial
__device__ inline float bits_to_normal(uint32_t bits)
{
  float f = __uint_as_float((bits >> 9) | 0x3F800000u) - 1.0f;
  const float lo = -0x1.fffffep-1f;
  float u = fmaxf(lo, f * 2.0f + lo);
  float w = -log1pf(-u * u);
  float p;
  if (w < 5.0f) {
    w -= 2.5f;
    p = 2.81022636e-08f;
    p = fmaf(p, w, 3.43273939e-07f);
    p = fmaf(p, w, -3.5233877e-06f);
    p = fmaf(p, w, -4.39150654e-06f);
    p = fmaf(p, w, 0.00021858087f);
    p = fmaf(p, w, -0.00125372503f);
    p = fmaf(p, w, -0.00417768164f);
    p = fmaf(p, w, 0.246640727f);
    p = fmaf(p, w, 1.50140941f);
  } else {
    w = sqrtf(w) - 3.0f;
    p = -0.000200214257f;
    p = fmaf(p, w, 0.000100950558f);
    p = fmaf(p, w, 0.00134934322f);
    p = fmaf(p, w, -0.00367342844f);
    p = fmaf(p, w, 0.00573950773f);
    p = fmaf(p, w, -0.0076224613f);
    p = fmaf(p, w, 0.00943887047f);
    p = fmaf(p, w, 1.00167406f);
    p = fmaf(p, w, 2.83297682f);
  }
  return 0x1.6a09e6p+0f * (p * u);
}

// ---------------- quantization helpers ----------------
__device__ inline float quantS8(float x)
{
  x = fminf(fmaxf(x, -0.9921875f), 0.9921875f);
  return rintf(x * 128.0f) * 0.0078125f;
}
__device__ inline float quantU8(float x)
{
  x = fminf(fmaxf(x, 0.0f), 1.0f);
  return rintf(x * 256.0f) * 0.00390625f;
}
__device__ inline float sigmoid_xla(float x) { return 0.5f + 0.5f * tanhf(0.5f * x); }

__device__ inline unsigned short f2bf(float x)
{
  uint32_t b = __float_as_uint(x);
  return (unsigned short)((b + 0x7FFFu + ((b >> 16) & 1u)) >> 16);
}
__device__ inline float bf2f(unsigned short u) { return __uint_as_float(((uint32_t)u) << 16); }

__device__ inline float dec_max(uint32_t u)
{
  uint32_t bits = (u & 0x80000000u) ? (u ^ 0x80000000u) : ~u;
  return __uint_as_float(bits);
}

// ---------------- small kernels ----------------
__global__ void init_max(uint32_t* mx)
{
  if (threadIdx.x < 4) mx[threadIdx.x] = 0u;
}

__global__ void kmax(const float4* __restrict__ a, int n4, uint32_t* __restrict__ out)
{
  float m = -3.4e38f;
  for (int i = blockIdx.x * blockDim.x + threadIdx.x; i < n4; i += gridDim.x * blockDim.x) {
    float4 v = a[i];
    m = fmaxf(fmaxf(m, fmaxf(v.x, v.y)), fmaxf(v.z, v.w));
  }
  for (int off = 32; off; off >>= 1) m = fmaxf(m, __shfl_down(m, off, 64));
  __shared__ float sm[4];
  if ((threadIdx.x & 63) == 0) sm[threadIdx.x >> 6] = m;
  __syncthreads();
  if (threadIdx.x == 0) {
    float bm = sm[0];
    for (int w = 1; w < (int)(blockDim.x >> 6); ++w) bm = fmaxf(bm, sm[w]);
    uint32_t bits = __float_as_uint(bm);
    uint32_t enc = (bits & 0x80000000u) ? ~bits : (bits | 0x80000000u);
    atomicMax(out, enc);
  }
}

__global__ void build_A(const float4* __restrict__ in, const float4* __restrict__ hx,
                        unsigned short* __restrict__ A)
{
  int t = blockIdx.x * 256 + threadIdx.x;
  int b = t >> 9;
  int kq = t & 511;
  float4 v = (kq < 256) ? in[b * 256 + kq] : hx[b * 256 + (kq - 256)];
  unsigned short o[4];
  o[0] = f2bf(quantS8(v.x)); o[1] = f2bf(quantS8(v.y));
  o[2] = f2bf(quantS8(v.z)); o[3] = f2bf(quantS8(v.w));
  *reinterpret_cast<uint64_t*>(A + (size_t)t * 4) = *reinterpret_cast<uint64_t*>(o);
}

// B^T with PERMUTED columns: original gate-col n (g=n>>10, h=n&1023) stored
// at row n' = 4h+g.  kc<2048: hi(Weff), kc>=2048: lo residual.
__global__ void build_B(const float* __restrict__ wih, const float* __restrict__ whh,
                        unsigned short* __restrict__ B, const uint32_t* __restrict__ mxenc,
                        uint32_t kih0, uint32_t kih1, uint32_t khh0, uint32_t khh1)
{
  uint32_t t = blockIdx.x * 256u + threadIdx.x;
  uint32_t arr = t >> 22;
  uint32_t r = t & 4194303u;
  uint32_t k = r & 1023u;
  uint32_t n = r >> 10;                       // original gate column
  const float* w = arr ? whh : wih;
  float mx = dec_max(mxenc[arr]);
  uint32_t key0 = arr ? khh0 : kih0, key1 = arr ? khh1 : kih1;
  uint32_t i = k * 4096u + n;                 // noise flat index (orig layout)
  float nrm = bits_to_normal(jax_bits32(key0, key1, i, 4194304u));
  float weff = w[(size_t)n * 1024u + k] + (nrm * mx) * 0.05f;
  unsigned short hi = f2bf(weff);
  unsigned short lob = f2bf(weff - bf2f(hi));
  uint32_t np = (n & 1023u) * 4u + (n >> 10); // permuted column
  size_t base = (size_t)np * 4096u + (arr ? 1024u : 0u) + k;
  B[base] = hi;
  B[base + 2048u] = lob;
}

__global__ void build_bias(const float* __restrict__ bih, const float* __restrict__ bhh,
                           float* __restrict__ biasE, const uint32_t* __restrict__ mxenc,
                           uint32_t kbi0, uint32_t kbi1, uint32_t kbh0, uint32_t kbh1)
{
  uint32_t j = blockIdx.x * 256u + threadIdx.x;
  if (j >= 4096u) return;
  float mi = dec_max(mxenc[2]), mh = dec_max(mxenc[3]);
  float ni = (bits_to_normal(jax_bits32(kbi0, kbi1, j, 4096u)) * mi) * 0.05f;
  float nh = (bits_to_normal(jax_bits32(kbh0, kbh1, j, 4096u)) * mh) * 0.05f;
  biasE[(j & 1023u) * 4u + (j >> 10)] = ((bih[j] + ni) + bhh[j]) + nh;
}

// ---------------- deep-pipelined MFMA GEMM + fused LSTM epilogue ------------
__device__ __forceinline__ void gload_lds16(const void* g, void* l)
{
  __builtin_amdgcn_global_load_lds((__attribute__((address_space(1))) void*)g,
                                   (__attribute__((address_space(3))) void*)l, 16, 0, 0);
}

#define VM4  asm volatile("s_waitcnt vmcnt(4)" ::: "memory")
#define VM0  asm volatile("s_waitcnt vmcnt(0)" ::: "memory")
#define NOVM

#define LGKM0 asm volatile("s_waitcnt lgkmcnt(0)" ::: "memory")
#define SBAR  __builtin_amdgcn_s_barrier()
#define SCB   __builtin_amdgcn_sched_barrier(0)

// One K-tile (BK=32), 2 phases of 16 MFMA each (acc quadrants m0-3 / m4-7).
// Phase skeleton (m201 template): reads+stage -> SCB -> SBAR -> lgkm0 -> SCB
// -> setprio1 -> 16 MFMA -> setprio0 -> SBAR.  Matrix pipe drains phase p
// while LDS pipe serves phase p+1's reads.
#define TILE_ONE(t_, DO_STAGE_, VM_ASM_)                                          \
  {                                                                               \
    const int buf_ = (t_) & 3;                                                    \
    const unsigned char* pa_ = lds + buf_ * 32768 + aoff;                         \
    const unsigned char* pb_ = lds + buf_ * 32768 + boff;                         \
    bf16x8 bfr_[4], afL_[4], afH_[4];                                             \
    /* ---- phase 0: reads (8) + A-half stage ---- */                             \
    _Pragma("unroll") for (int n_ = 0; n_ < 4; ++n_)                              \
      bfr_[n_] = *(const bf16x8*)(pb_ + n_ * 1024);                               \
    _Pragma("unroll") for (int m_ = 0; m_ < 4; ++m_)                              \
      afL_[m_] = *(const bf16x8*)(pa_ + m_ * 1024);                               \
    if (DO_STAGE_) {                                                              \
      const int ts_ = (t_) + 2;                                                   \
      unsigned char* la_ = lds + (ts_ & 3) * 32768;                               \
      const int ka_ = (ts_ * 32) & 2047;                                          \
      gload_lds16(Ar0 + ka_, la_ + tid * 16);                                     \
      gload_lds16(Ar1 + ka_, la_ + 8192 + tid * 16);                              \
    }                                                                             \
    SCB; SBAR; LGKM0; SCB;                                                        \
    __builtin_amdgcn_s_setprio(1);                                                \
    _Pragma("unroll") for (int m_ = 0; m_ < 4; ++m_)                              \
      _Pragma("unroll") for (int n_ = 0; n_ < 4; ++n_)                            \
        acc[m_][n_] = __builtin_amdgcn_mfma_f32_16x16x32_bf16(afL_[m_], bfr_[n_], \
                                                              acc[m_][n_], 0, 0, 0); \
    __builtin_amdgcn_s_setprio(0);                                                \
    SBAR;                                                                         \
    /* ---- phase 1: reads (4) + B-half stage ---- */                             \
    _Pragma("unroll") for (int m_ = 0; m_ < 4; ++m_)                              \
      afH_[m_] = *(const bf16x8*)(pa_ + (4 + m_) * 1024);                         \
    if (DO_STAGE_) {                                                              \
      const int ts_ = (t_) + 2;                                                   \
      unsigned char* lb_ = lds + (ts_ & 3) * 32768 + 16384;                       \
      const size_t kb_ = (size_t)ts_ * 32;                                        \
      gload_lds16(Br0 + kb_, lb_ + tid * 16);                                     \
      gload_lds16(Br1 + kb_, lb_ + 8192 + tid * 16);                              \
    }                                                                             \
    VM_ASM_;                                                                      \
    SCB; SBAR; LGKM0; SCB;                                                        \
    __builtin_amdgcn_s_setprio(1);                                                \
    _Pragma("unroll") for (int m_ = 0; m_ < 4; ++m_)                              \
      _Pragma("unroll") for (int n_ = 0; n_ < 4; ++n_)                            \
        acc[4 + m_][n_] = __builtin_amdgcn_mfma_f32_16x16x32_bf16(afH_[m_], bfr_[n_], \
                                                              acc[4 + m_][n_], 0, 0, 0); \
    __builtin_amdgcn_s_setprio(0);                                                \
    SBAR;                                                                         \
  }

__global__ __launch_bounds__(512, 2) void gemm_gates(
    const unsigned short* __restrict__ A,   // [4096][2048] bf16 bits
    const unsigned short* __restrict__ B,   // [4096][4096] bf16 bits, permuted cols
    const float* __restrict__ bias,         // [4096] permuted
    const float* __restrict__ cx,           // [4096][1024]
    float* __restrict__ hy,                 // [4096][1024]
    float* __restrict__ cy)                 // [4096][1024]
{
  extern __shared__ unsigned char lds[];    // 128KB
  const int tid  = threadIdx.x;
  const int lane = tid & 63;
  const int wave = tid >> 6;
  const int wr = wave >> 2;                 // 0..1  (M)
  const int wc = wave & 3;                  // 0..3  (N)

  const int bid = blockIdx.x;
  const int wg  = (bid & 7) * 32 + (bid >> 3);
  const int brow = (wg & 15) * 256;
  const int bcol = (wg >> 4) * 256;

  // staging source (inverse-swizzled): chunk c -> p=c>>3, lc=(c&7)^(p&7)
  int sr0, sk0, sr1, sk1;
  {
    int c = tid, p = c >> 3, lc = (c & 7) ^ (p & 7);
    sr0 = p * 2 + (lc >> 2); sk0 = (lc & 3) * 8;
    c = tid + 512; p = c >> 3; lc = (c & 7) ^ (p & 7);
    sr1 = p * 2 + (lc >> 2); sk1 = (lc & 3) * 8;
  }
  const unsigned short* Ar0 = A + (size_t)(brow + sr0) * 2048 + sk0;
  const unsigned short* Ar1 = A + (size_t)(brow + sr1) * 2048 + sk1;
  const unsigned short* Br0 = B + (size_t)(bcol + sr0) * 4096 + sk0;
  const unsigned short* Br1 = B + (size_t)(bcol + sr1) * 4096 + sk1;

  const int lrh = (lane & 15) >> 1;
  const int chk = ((((lane & 1) << 2) | (lane >> 4)) ^ lrh);
  const int aoff = wr * 8192 + lrh * 128 + chk * 16;
  const int boff = 16384 + wc * 4096 + lrh * 128 + chk * 16;

  f32x4 acc[8][4] = {};

  // prologue: stage tiles 0,1
#pragma unroll
  for (int tt = 0; tt < 2; ++tt) {
    unsigned char* la = lds + tt * 32768;
    const int ka = tt * 32;
    gload_lds16(Ar0 + ka, la + tid * 16);
    gload_lds16(Ar1 + ka, la + 8192 + tid * 16);
    gload_lds16(Br0 + (size_t)(tt * 32), la + 16384 + tid * 16);
    gload_lds16(Br1 + (size_t)(tt * 32), la + 16384 + 8192 + tid * 16);
  }
  VM4;
  SBAR; SCB;

#pragma unroll 1
  for (int t = 0; t < 126; ++t) {
    TILE_ONE(t, 1, VM4);
  }
  TILE_ONE(126, 0, VM0);
  TILE_ONE(127, 0, NOVM);

  // ---- fused LSTM epilogue ----
  // acc[am][n] row = brow + wr*128 + am*16 + (lane>>4)*4 + r
  //            col = bcol + wc*64 + n*16 + (lane&15)   (permuted: col = 4h+g)
  float* LT = (float*)lds;
  const int col_local0 = wc * 64 + (lane & 15);
  const int lrow = (lane >> 4) << 2;
  const int h = tid & 63;
  const int hg = (bcol >> 2) + h;

#pragma unroll
  for (int hh = 0; hh < 2; ++hh) {
    __syncthreads();                       // previous half's reads done
#pragma unroll
    for (int m = 0; m < 4; ++m) {
#pragma unroll
      for (int n = 0; n < 4; ++n) {
        const int cl = col_local0 + n * 16;
        const float bv = bias[bcol + cl];
        const int lr0 = wr * 64 + m * 16 + lrow;
#pragma unroll
        for (int r = 0; r < 4; ++r)
          LT[(lr0 + r) * 256 + cl] = acc[hh * 4 + m][n][r] + bv;
      }
    }
    __syncthreads();
#pragma unroll
    for (int i = 0; i < 16; ++i) {
      const int lr = (tid >> 6) * 16 + i;                       // 0..127
      const int grow = brow + ((lr >> 6) << 7) + hh * 64 + (lr & 63);
      const float4 q = *(const float4*)(LT + lr * 256 + 4 * h); // (in,fg,cell,out)
      const size_t oidx = (size_t)grow * 1024 + hg;
      float ing = quantU8(sigmoid_xla(q.x));
      float fg  = quantU8(sigmoid_xla(q.y));
      float cg  = quantS8(tanhf(q.z));
      float og  = quantU8(sigmoid_xla(q.w));
      float c0  = cx[oidx];
      float cyv = quantS8((quantS8(fg * c0) + quantS8(ing * cg)) * 0.5f);
      float hyv = quantS8(og * quantS8(tanhf(cyv * 2.0f)));
      hy[oidx] = hyv;
      cy[oidx] = cyv;
    }
  }
}

// ---------------- host ----------------
extern "C" void kernel_launch(void* const* d_in, const int* in_sizes, int n_in,
                              void* d_out, int out_size, void* d_ws, size_t ws_size,
                              hipStream_t stream)
{
  const float* input = (const float*)d_in[0];
  const float* hx    = (const float*)d_in[1];
  const float* cx    = (const float*)d_in[2];
  const float* wih   = (const float*)d_in[3];
  const float* whh   = (const float*)d_in[4];
  const float* bih   = (const float*)d_in[5];
  const float* bhh   = (const float*)d_in[6];
  (void)in_sizes; (void)n_in; (void)ws_size;

  uint8_t* ws = (uint8_t*)d_ws;
  unsigned short* A   = (unsigned short*)(ws + WS_A_OFF);
  unsigned short* B   = (unsigned short*)(ws + WS_B_OFF);
  float* biasE        = (float*)(ws + WS_BIAS_OFF);
  uint32_t* mx        = (uint32_t*)(ws + WS_MAX_OFF);

  uint32_t nk[4][2];
#if PART
  for (int i = 0; i < 4; ++i) tf2x32(0u, 42u, 0u, (uint32_t)i, nk[i][0], nk[i][1]);
#else
  {
    uint32_t w0[4], w1[4];
    for (int i = 0; i < 4; ++i) tf2x32(0u, 42u, (uint32_t)i, (uint32_t)(i + 4), w0[i], w1[i]);
    uint32_t out8[8] = {w0[0], w0[1], w0[2], w0[3], w1[0], w1[1], w1[2], w1[3]};
    for (int i = 0; i < 4; ++i) { nk[i][0] = out8[2 * i]; nk[i][1] = out8[2 * i + 1]; }
  }
#endif

  init_max<<<1, 64, 0, stream>>>(mx);
  kmax<<<1024, 256, 0, stream>>>((const float4*)wih, 1048576, mx + 0);
  kmax<<<1024, 256, 0, stream>>>((const float4*)whh, 1048576, mx + 1);
  kmax<<<4, 256, 0, stream>>>((const float4*)bih, 1024, mx + 2);
  kmax<<<4, 256, 0, stream>>>((const float4*)bhh, 1024, mx + 3);

  build_A<<<8192, 256, 0, stream>>>((const float4*)input, (const float4*)hx, A);
  build_B<<<32768, 256, 0, stream>>>(wih, whh, B, mx, nk[0][0], nk[0][1], nk[1][0], nk[1][1]);
  build_bias<<<16, 256, 0, stream>>>(bih, bhh, biasE, mx, nk[2][0], nk[2][1], nk[3][0], nk[3][1]);

  float* hy = (float*)d_out;
  float* cyp = hy + (size_t)BATCH * 1024;

  (void)hipFuncSetAttribute((const void*)gemm_gates,
                            hipFuncAttributeMaxDynamicSharedMemorySize, 131072);
  gemm_gates<<<dim3(256), dim3(512), 131072, stream>>>(A, B, biasE, cx, hy, cyp);
}